// Round 1
// baseline (433.960 us; speedup 1.0000x reference)
//
#include <hip/hip_runtime.h>
#include <math.h>

#define B 64
#define T 2048
#define DS 512
#define DH 512
#define DA 512

// Kernel A: phi_s[b,a] = dot(s[b,:], phi_w[a,:]) + phi_b[a]
// One wave per output element; lanes split K (512) into 8 floats/lane (2x float4).
__global__ __launch_bounds__(256) void k_phi(const float* __restrict__ s,
                                             const float* __restrict__ phi_w,
                                             const float* __restrict__ phi_b,
                                             float* __restrict__ phi_s) {
    const int wave = threadIdx.x >> 6;
    const int lane = threadIdx.x & 63;
    const int out  = blockIdx.x * 4 + wave;   // [0, B*DA)
    const int b = out >> 9;                    // /512
    const int a = out & 511;

    const float4* s4 = (const float4*)(s + (size_t)b * DS);
    const float4* w4 = (const float4*)(phi_w + (size_t)a * DS);
    float4 sA = s4[lane * 2], sB = s4[lane * 2 + 1];
    float4 wA = w4[lane * 2], wB = w4[lane * 2 + 1];
    float acc = sA.x * wA.x + sA.y * wA.y + sA.z * wA.z + sA.w * wA.w
              + sB.x * wB.x + sB.y * wB.y + sB.z * wB.z + sB.w * wB.w;
    #pragma unroll
    for (int off = 32; off > 0; off >>= 1)
        acc += __shfl_down(acc, off, 64);
    if (lane == 0) phi_s[out] = acc + phi_b[a];
}

// Kernel B: v[b,k] = sum_a phi_s[b,a] * psi_w[a,k]
// One block per b; 128 threads each own 4 consecutive k (float4) -> fully
// coalesced psi_w reads (wave reads 1 KiB contiguous per a-iter).
__global__ __launch_bounds__(128) void k_v(const float* __restrict__ phi_s,
                                           const float* __restrict__ psi_w,
                                           float* __restrict__ v) {
    __shared__ float ps[DA];
    const int b = blockIdx.x;
    const int tid = threadIdx.x;
    ((float4*)ps)[tid] = ((const float4*)(phi_s + (size_t)b * DA))[tid];
    __syncthreads();

    const float4* w4 = (const float4*)psi_w;   // [a][DH/4]
    float4 acc = {0.f, 0.f, 0.f, 0.f};
    #pragma unroll 4
    for (int a = 0; a < DA; ++a) {
        const float p = ps[a];                 // LDS broadcast, conflict-free
        const float4 w = w4[a * (DH / 4) + tid];
        acc.x += p * w.x; acc.y += p * w.y; acc.z += p * w.z; acc.w += p * w.w;
    }
    ((float4*)(v + (size_t)b * DH))[tid] = acc;
}

// Kernel C (the HBM-bound pass): e[b,t] = v[b] . h[b,t];  rs[b,t] = sum_k h[b,t,k]
// One wave per (b,t) row; 8 floats/lane (2x float4), dual shuffle reduce.
__global__ __launch_bounds__(256) void k_scores(const float* __restrict__ h,
                                                const float* __restrict__ v,
                                                float* __restrict__ e,
                                                float* __restrict__ rs) {
    const int wave = threadIdx.x >> 6;
    const int lane = threadIdx.x & 63;
    const int row  = blockIdx.x * 4 + wave;    // [0, B*T)
    const int b = row >> 11;                    // /T

    const float4* h4 = (const float4*)(h + (size_t)row * DH);
    const float4* v4 = (const float4*)(v + (size_t)b * DH);
    float4 hA = h4[lane * 2], hB = h4[lane * 2 + 1];
    float4 vA = v4[lane * 2], vB = v4[lane * 2 + 1];

    float dot = hA.x * vA.x + hA.y * vA.y + hA.z * vA.z + hA.w * vA.w
              + hB.x * vB.x + hB.y * vB.y + hB.z * vB.z + hB.w * vB.w;
    float sum = hA.x + hA.y + hA.z + hA.w + hB.x + hB.y + hB.z + hB.w;
    #pragma unroll
    for (int off = 32; off > 0; off >>= 1) {
        dot += __shfl_down(dot, off, 64);
        sum += __shfl_down(sum, off, 64);
    }
    if (lane == 0) { e[row] = dot; rs[row] = sum; }
}

// Kernel D: per-b softmax over t, fused with rowsum multiply.
// 256 threads, 8 e-values per thread kept in registers.
__global__ __launch_bounds__(256) void k_softmax(const float* __restrict__ e,
                                                 const float* __restrict__ rs,
                                                 float* __restrict__ c) {
    __shared__ float red[256];
    const int b = blockIdx.x;
    const int tid = threadIdx.x;
    const float* eb = e + (size_t)b * T;

    float ev[8];
    float m = -INFINITY;
    #pragma unroll
    for (int i = 0; i < 8; ++i) {
        ev[i] = eb[tid + i * 256];
        m = fmaxf(m, ev[i]);
    }
    red[tid] = m; __syncthreads();
    #pragma unroll
    for (int s2 = 128; s2 > 0; s2 >>= 1) {
        if (tid < s2) red[tid] = fmaxf(red[tid], red[tid + s2]);
        __syncthreads();
    }
    m = red[0];
    __syncthreads();

    float lsum = 0.f;
    #pragma unroll
    for (int i = 0; i < 8; ++i) {
        ev[i] = expf(ev[i] - m);
        lsum += ev[i];
    }
    red[tid] = lsum; __syncthreads();
    #pragma unroll
    for (int s2 = 128; s2 > 0; s2 >>= 1) {
        if (tid < s2) red[tid] += red[tid + s2];
        __syncthreads();
    }
    const float inv = 1.0f / red[0];

    const float* rb = rs + (size_t)b * T;
    float* cb = c + (size_t)b * T;
    #pragma unroll
    for (int i = 0; i < 8; ++i)
        cb[tid + i * 256] = ev[i] * inv * rb[tid + i * 256];
}

extern "C" void kernel_launch(void* const* d_in, const int* in_sizes, int n_in,
                              void* d_out, int out_size, void* d_ws, size_t ws_size,
                              hipStream_t stream) {
    const float* s     = (const float*)d_in[0];
    const float* h     = (const float*)d_in[1];
    const float* phi_w = (const float*)d_in[2];
    const float* phi_b = (const float*)d_in[3];
    const float* psi_w = (const float*)d_in[4];
    // d_in[5] = psi_b: adds a per-b constant to e[b,:] -> cancels in softmax.
    (void)in_sizes; (void)n_in; (void)out_size; (void)ws_size;

    float* out = (float*)d_out;
    float* ws  = (float*)d_ws;
    float* phi_s = ws;                    // B*DA   floats (128 KB)
    float* v     = phi_s + B * DA;        // B*DH   floats (128 KB)
    float* e     = v + B * DH;            // B*T    floats (512 KB)
    float* rs    = e + B * T;             // B*T    floats (512 KB)

    k_phi    <<<B * DA / 4, 256, 0, stream>>>(s, phi_w, phi_b, phi_s);
    k_v      <<<B,          128, 0, stream>>>(phi_s, psi_w, v);
    k_scores <<<B * T / 4,  256, 0, stream>>>(h, v, e, rs);
    k_softmax<<<B,          256, 0, stream>>>(e, rs, out);
}

// Round 3
// 394.110 us; speedup vs baseline: 1.1011x; 1.1011x over previous
//
#include <hip/hip_runtime.h>
#include <math.h>

#define B 64
#define T 2048
#define DS 512
#define DH 512
#define DA 512

typedef float fx4 __attribute__((ext_vector_type(4)));  // native vec: nt-load OK

// Kernel A: phi_s[b,a] = dot(s[b,:], phi_w[a,:]) + phi_b[a]
// One wave per output element; lanes split K (512) into 8 floats/lane (2x float4).
__global__ __launch_bounds__(256) void k_phi(const float* __restrict__ s,
                                             const float* __restrict__ phi_w,
                                             const float* __restrict__ phi_b,
                                             float* __restrict__ phi_s) {
    const int wave = threadIdx.x >> 6;
    const int lane = threadIdx.x & 63;
    const int out  = blockIdx.x * 4 + wave;   // [0, B*DA)
    const int b = out >> 9;                    // /512
    const int a = out & 511;

    const fx4* s4 = (const fx4*)(s + (size_t)b * DS);
    const fx4* w4 = (const fx4*)(phi_w + (size_t)a * DS);
    fx4 sA = s4[lane * 2], sB = s4[lane * 2 + 1];
    fx4 wA = w4[lane * 2], wB = w4[lane * 2 + 1];
    float acc = sA.x * wA.x + sA.y * wA.y + sA.z * wA.z + sA.w * wA.w
              + sB.x * wB.x + sB.y * wB.y + sB.z * wB.z + sB.w * wB.w;
    #pragma unroll
    for (int off = 32; off > 0; off >>= 1)
        acc += __shfl_down(acc, off, 64);
    if (lane == 0) phi_s[out] = acc + phi_b[a];
}

// Kernel B: vp[q][b][k] = sum_{a in q-th quarter} phi_s[b,a] * psi_w[a,k]
// 4-way split over the a-reduction -> 256 blocks (vs 64) to cut the
// latency-bound serial chain 4x. k_scores sums the 4 partials (L2-hot).
__global__ __launch_bounds__(128) void k_v(const float* __restrict__ phi_s,
                                           const float* __restrict__ psi_w,
                                           float* __restrict__ vp) {
    __shared__ float ps[DA / 4];
    const int b = blockIdx.x >> 2;
    const int q = blockIdx.x & 3;
    const int tid = threadIdx.x;
    ps[tid] = phi_s[(size_t)b * DA + q * (DA / 4) + tid];
    __syncthreads();

    const fx4* w4 = (const fx4*)psi_w;   // [a][DH/4]
    fx4 acc = {0.f, 0.f, 0.f, 0.f};
    #pragma unroll 8
    for (int a = 0; a < DA / 4; ++a) {
        const float p = ps[a];                 // LDS broadcast, conflict-free
        const fx4 w = w4[(q * (DA / 4) + a) * (DH / 4) + tid];
        acc += p * w;
    }
    ((fx4*)(vp + ((size_t)q * B + b) * DH))[tid] = acc;
}

// Kernel C (the HBM-bound pass): e[b,t] = v[b] . h[b,t];  rs[b,t] = sum_k h[b,t,k]
// One wave per (b,t) row; 8 floats/lane (2x float4), dual shuffle reduce.
// h is streamed once -> non-temporal loads to avoid cache pollution.
__global__ __launch_bounds__(256) void k_scores(const float* __restrict__ h,
                                                const float* __restrict__ vp,
                                                float* __restrict__ e,
                                                float* __restrict__ rs) {
    const int wave = threadIdx.x >> 6;
    const int lane = threadIdx.x & 63;
    const int row  = blockIdx.x * 4 + wave;    // [0, B*T)
    const int b = row >> 11;                    // /T

    const fx4* h4 = (const fx4*)(h + (size_t)row * DH);
    fx4 hA = __builtin_nontemporal_load(&h4[lane * 2]);
    fx4 hB = __builtin_nontemporal_load(&h4[lane * 2 + 1]);

    // sum the 4 a-split partials of v[b] (all L2-hot, 2 MB total working set)
    fx4 vA = {0.f, 0.f, 0.f, 0.f}, vB = {0.f, 0.f, 0.f, 0.f};
    #pragma unroll
    for (int q = 0; q < 4; ++q) {
        const fx4* v4 = (const fx4*)(vp + ((size_t)q * B + b) * DH);
        vA += v4[lane * 2];
        vB += v4[lane * 2 + 1];
    }

    float dot = hA.x * vA.x + hA.y * vA.y + hA.z * vA.z + hA.w * vA.w
              + hB.x * vB.x + hB.y * vB.y + hB.z * vB.z + hB.w * vB.w;
    float sum = hA.x + hA.y + hA.z + hA.w + hB.x + hB.y + hB.z + hB.w;
    #pragma unroll
    for (int off = 32; off > 0; off >>= 1) {
        dot += __shfl_down(dot, off, 64);
        sum += __shfl_down(sum, off, 64);
    }
    if (lane == 0) { e[row] = dot; rs[row] = sum; }
}

// Kernel D: per-b softmax over t, fused with rowsum multiply.
// 256 threads, 8 e-values per thread kept in registers.
__global__ __launch_bounds__(256) void k_softmax(const float* __restrict__ e,
                                                 const float* __restrict__ rs,
                                                 float* __restrict__ c) {
    __shared__ float red[256];
    const int b = blockIdx.x;
    const int tid = threadIdx.x;
    const float* eb = e + (size_t)b * T;

    float ev[8];
    float m = -INFINITY;
    #pragma unroll
    for (int i = 0; i < 8; ++i) {
        ev[i] = eb[tid + i * 256];
        m = fmaxf(m, ev[i]);
    }
    red[tid] = m; __syncthreads();
    #pragma unroll
    for (int s2 = 128; s2 > 0; s2 >>= 1) {
        if (tid < s2) red[tid] = fmaxf(red[tid], red[tid + s2]);
        __syncthreads();
    }
    m = red[0];
    __syncthreads();

    float lsum = 0.f;
    #pragma unroll
    for (int i = 0; i < 8; ++i) {
        ev[i] = expf(ev[i] - m);
        lsum += ev[i];
    }
    red[tid] = lsum; __syncthreads();
    #pragma unroll
    for (int s2 = 128; s2 > 0; s2 >>= 1) {
        if (tid < s2) red[tid] += red[tid + s2];
        __syncthreads();
    }
    const float inv = 1.0f / red[0];

    const float* rb = rs + (size_t)b * T;
    float* cb = c + (size_t)b * T;
    #pragma unroll
    for (int i = 0; i < 8; ++i)
        cb[tid + i * 256] = ev[i] * inv * rb[tid + i * 256];
}

extern "C" void kernel_launch(void* const* d_in, const int* in_sizes, int n_in,
                              void* d_out, int out_size, void* d_ws, size_t ws_size,
                              hipStream_t stream) {
    const float* s     = (const float*)d_in[0];
    const float* h     = (const float*)d_in[1];
    const float* phi_w = (const float*)d_in[2];
    const float* phi_b = (const float*)d_in[3];
    const float* psi_w = (const float*)d_in[4];
    // d_in[5] = psi_b: adds a per-b constant to e[b,:] -> cancels in softmax.
    (void)in_sizes; (void)n_in; (void)out_size; (void)ws_size;

    float* out = (float*)d_out;
    float* ws  = (float*)d_ws;
    float* phi_s = ws;                    // B*DA     floats (128 KB)
    float* vp    = phi_s + B * DA;        // 4*B*DH   floats (512 KB)
    float* e     = vp + 4 * B * DH;       // B*T      floats (512 KB)
    float* rs    = e + B * T;             // B*T      floats (512 KB)

    k_phi    <<<B * DA / 4, 256, 0, stream>>>(s, phi_w, phi_b, phi_s);
    k_v      <<<B * 4,      128, 0, stream>>>(phi_s, psi_w, vp);
    k_scores <<<B * T / 4,  256, 0, stream>>>(h, vp, e, rs);
    k_softmax<<<B,          256, 0, stream>>>(e, rs, out);
}

// Round 4
// 375.974 us; speedup vs baseline: 1.1542x; 1.0482x over previous
//
#include <hip/hip_runtime.h>
#include <math.h>

#define B 64
#define T 2048
#define DS 512
#define DH 512
#define DA 512

typedef float fx4 __attribute__((ext_vector_type(4)));  // native vec: nt-load OK
typedef float fx2 __attribute__((ext_vector_type(2)));

// Kernel A: phi_s[b,a] = dot(s[b,:], phi_w[a,:]) + phi_b[a]
// One wave per output element; lanes split K (512) into 8 floats/lane (2x float4).
__global__ __launch_bounds__(256) void k_phi(const float* __restrict__ s,
                                             const float* __restrict__ phi_w,
                                             const float* __restrict__ phi_b,
                                             float* __restrict__ phi_s) {
    const int wave = threadIdx.x >> 6;
    const int lane = threadIdx.x & 63;
    const int out  = blockIdx.x * 4 + wave;   // [0, B*DA)
    const int b = out >> 9;                    // /512
    const int a = out & 511;

    const fx4* s4 = (const fx4*)(s + (size_t)b * DS);
    const fx4* w4 = (const fx4*)(phi_w + (size_t)a * DS);
    fx4 sA = s4[lane * 2], sB = s4[lane * 2 + 1];
    fx4 wA = w4[lane * 2], wB = w4[lane * 2 + 1];
    float acc = sA.x * wA.x + sA.y * wA.y + sA.z * wA.z + sA.w * wA.w
              + sB.x * wB.x + sB.y * wB.y + sB.z * wB.z + sB.w * wB.w;
    #pragma unroll
    for (int off = 32; off > 0; off >>= 1)
        acc += __shfl_down(acc, off, 64);
    if (lane == 0) phi_s[out] = acc + phi_b[a];
}

// Kernel B: vp[q][b][k] = sum_{a in q-th quarter} phi_s[b,a] * psi_w[a,k]
// 4-way split over the a-reduction -> 256 blocks to cut the latency-bound
// serial chain 4x. k_scores sums the 4 partials once per block (LDS-staged).
__global__ __launch_bounds__(128) void k_v(const float* __restrict__ phi_s,
                                           const float* __restrict__ psi_w,
                                           float* __restrict__ vp) {
    __shared__ float ps[DA / 4];
    const int b = blockIdx.x >> 2;
    const int q = blockIdx.x & 3;
    const int tid = threadIdx.x;
    ps[tid] = phi_s[(size_t)b * DA + q * (DA / 4) + tid];
    __syncthreads();

    const fx4* w4 = (const fx4*)psi_w;   // [a][DH/4]
    fx4 acc = {0.f, 0.f, 0.f, 0.f};
    #pragma unroll 8
    for (int a = 0; a < DA / 4; ++a) {
        const float p = ps[a];                 // LDS broadcast, conflict-free
        const fx4 w = w4[(q * (DA / 4) + a) * (DH / 4) + tid];
        acc += p * w;
    }
    ((fx4*)(vp + ((size_t)q * B + b) * DH))[tid] = acc;
}

// Kernel C (the HBM-bound pass): e[b,t] = v[b] . h[b,t];  rs[b,t] = sum_k h[b,t,k]
// 16 rows per block (all same b): q-summed v[b] staged in LDS once per block,
// each wave keeps its v fragment in registers and streams 4 rows of h with
// batched non-temporal loads (8 dwordx4 in flight).
__global__ __launch_bounds__(256) void k_scores(const float* __restrict__ h,
                                                const float* __restrict__ vp,
                                                float* __restrict__ e,
                                                float* __restrict__ rs) {
    __shared__ float vsum[DH];
    const int tid  = threadIdx.x;
    const int base = blockIdx.x * 16;          // row base; 16 | T so same b
    const int b    = base >> 11;               // /T

    // stage q-summed v[b]: 256 threads x 2 floats, 8 KB of L2 reads per block
    {
        fx2 acc = {0.f, 0.f};
        #pragma unroll
        for (int q = 0; q < 4; ++q) {
            const fx2* v2 = (const fx2*)(vp + ((size_t)q * B + b) * DH);
            acc += v2[tid];
        }
        ((fx2*)vsum)[tid] = acc;
    }
    __syncthreads();

    const int wave = tid >> 6;
    const int lane = tid & 63;
    const fx4 vA = ((const fx4*)vsum)[lane * 2];
    const fx4 vB = ((const fx4*)vsum)[lane * 2 + 1];

    const int row0 = base + wave * 4;
    fx4 hA[4], hB[4];
    #pragma unroll
    for (int r = 0; r < 4; ++r) {
        const fx4* h4 = (const fx4*)(h + (size_t)(row0 + r) * DH);
        hA[r] = __builtin_nontemporal_load(&h4[lane * 2]);
        hB[r] = __builtin_nontemporal_load(&h4[lane * 2 + 1]);
    }

    float dot[4], sum[4];
    #pragma unroll
    for (int r = 0; r < 4; ++r) {
        dot[r] = hA[r].x * vA.x + hA[r].y * vA.y + hA[r].z * vA.z + hA[r].w * vA.w
               + hB[r].x * vB.x + hB[r].y * vB.y + hB[r].z * vB.z + hB[r].w * vB.w;
        sum[r] = hA[r].x + hA[r].y + hA[r].z + hA[r].w
               + hB[r].x + hB[r].y + hB[r].z + hB[r].w;
    }
    #pragma unroll
    for (int off = 32; off > 0; off >>= 1) {
        #pragma unroll
        for (int r = 0; r < 4; ++r) {
            dot[r] += __shfl_down(dot[r], off, 64);
            sum[r] += __shfl_down(sum[r], off, 64);
        }
    }
    if (lane == 0) {
        #pragma unroll
        for (int r = 0; r < 4; ++r) { e[row0 + r] = dot[r]; rs[row0 + r] = sum[r]; }
    }
}

// Kernel D: per-b softmax over t, fused with rowsum multiply.
// 256 threads, 8 e-values per thread kept in registers.
__global__ __launch_bounds__(256) void k_softmax(const float* __restrict__ e,
                                                 const float* __restrict__ rs,
                                                 float* __restrict__ c) {
    __shared__ float red[256];
    const int b = blockIdx.x;
    const int tid = threadIdx.x;
    const float* eb = e + (size_t)b * T;

    float ev[8];
    float m = -INFINITY;
    #pragma unroll
    for (int i = 0; i < 8; ++i) {
        ev[i] = eb[tid + i * 256];
        m = fmaxf(m, ev[i]);
    }
    red[tid] = m; __syncthreads();
    #pragma unroll
    for (int s2 = 128; s2 > 0; s2 >>= 1) {
        if (tid < s2) red[tid] = fmaxf(red[tid], red[tid + s2]);
        __syncthreads();
    }
    m = red[0];
    __syncthreads();

    float lsum = 0.f;
    #pragma unroll
    for (int i = 0; i < 8; ++i) {
        ev[i] = expf(ev[i] - m);
        lsum += ev[i];
    }
    red[tid] = lsum; __syncthreads();
    #pragma unroll
    for (int s2 = 128; s2 > 0; s2 >>= 1) {
        if (tid < s2) red[tid] += red[tid + s2];
        __syncthreads();
    }
    const float inv = 1.0f / red[0];

    const float* rb = rs + (size_t)b * T;
    float* cb = c + (size_t)b * T;
    #pragma unroll
    for (int i = 0; i < 8; ++i)
        cb[tid + i * 256] = ev[i] * inv * rb[tid + i * 256];
}

extern "C" void kernel_launch(void* const* d_in, const int* in_sizes, int n_in,
                              void* d_out, int out_size, void* d_ws, size_t ws_size,
                              hipStream_t stream) {
    const float* s     = (const float*)d_in[0];
    const float* h     = (const float*)d_in[1];
    const float* phi_w = (const float*)d_in[2];
    const float* phi_b = (const float*)d_in[3];
    const float* psi_w = (const float*)d_in[4];
    // d_in[5] = psi_b: adds a per-b constant to e[b,:] -> cancels in softmax.
    (void)in_sizes; (void)n_in; (void)out_size; (void)ws_size;

    float* out = (float*)d_out;
    float* ws  = (float*)d_ws;
    float* phi_s = ws;                    // B*DA     floats (128 KB)
    float* vp    = phi_s + B * DA;        // 4*B*DH   floats (512 KB)
    float* e     = vp + 4 * B * DH;       // B*T      floats (512 KB)
    float* rs    = e + B * T;             // B*T      floats (512 KB)

    k_phi    <<<B * DA / 4, 256, 0, stream>>>(s, phi_w, phi_b, phi_s);
    k_v      <<<B * 4,      128, 0, stream>>>(phi_s, psi_w, vp);
    k_scores <<<B * T / 16, 256, 0, stream>>>(h, vp, e, rs);
    k_softmax<<<B,          256, 0, stream>>>(e, rs, out);
}